// Round 15
// baseline (76.150 us; speedup 1.0000x reference)
//
#include <hip/hip_runtime.h>
#include <cstdint>
#include <cstddef>

#define BATCH 4
#define CIN   512
#define NPIX  1024
#define HEADS 16
#define DH    32
#define DATTN 512
#define O_QKV 1536

typedef unsigned short u16;
typedef __bf16 bf16x4 __attribute__((ext_vector_type(4)));
typedef __bf16 bf16x8 __attribute__((ext_vector_type(8)));
typedef float  f32x4  __attribute__((ext_vector_type(4)));

typedef const __attribute__((address_space(1))) void g1_t;
typedef __attribute__((address_space(3))) void l3_t;

#if defined(__has_builtin)
#if __has_builtin(__builtin_amdgcn_exp2f)
#define EXP2(x) __builtin_amdgcn_exp2f(x)
#endif
#endif
#ifndef EXP2
#define EXP2(x) __expf((x) * 0.6931471805599453f)
#endif

__device__ __forceinline__ u16 f2bf(float f) {
  unsigned u = __float_as_uint(f);
  u += 0x7fffu + ((u >> 16) & 1u);
  return (u16)(u >> 16);
}

// async global->LDS, 16B per lane; lp must be wave-uniform (HW: base + lane*16)
__device__ __forceinline__ void gl_lds16(const void* gp, void* lp) {
  __builtin_amdgcn_global_load_lds((g1_t*)gp, (l3_t*)lp, 16, 0, 0);
}

// ---------------------------------------------------------------------------
// prep_w: convert w_qkv [1536][512] and w_proj [512][512] f32 -> bf16.
// ---------------------------------------------------------------------------
__global__ __launch_bounds__(256) void prep_w(const float* __restrict__ w1,
                                              const float* __restrict__ w2,
                                              u16* __restrict__ o1,
                                              u16* __restrict__ o2) {
  const int idx = blockIdx.x * 256 + threadIdx.x;   // float4 index
  const int n1 = (O_QKV * CIN) >> 2;                // 196608
  float4 v = (idx < n1) ? reinterpret_cast<const float4*>(w1)[idx]
                        : reinterpret_cast<const float4*>(w2)[idx - n1];
  uint2 pk = make_uint2((unsigned)f2bf(v.x) | ((unsigned)f2bf(v.y) << 16),
                        (unsigned)f2bf(v.z) | ((unsigned)f2bf(v.w) << 16));
  if (idx < n1) reinterpret_cast<uint2*>(o1)[idx] = pk;
  else          reinterpret_cast<uint2*>(o2)[idx - n1] = pk;
}

// ---------------------------------------------------------------------------
// prep_x: x [B][C][N] f32 -> xt [B][N][C] bf16 (tiled 64x64 LDS transpose)
// ---------------------------------------------------------------------------
__global__ __launch_bounds__(256) void prep_x(const float* __restrict__ x,
                                              u16* __restrict__ xt) {
  __shared__ float sT[64][65];
  const int t  = threadIdx.x;
  const int n0 = blockIdx.x * 64;
  const int c0 = blockIdx.y * 64;
  const int b  = blockIdx.z;
  const float* xb = x + ((size_t)b * CIN + c0) * NPIX + n0;
#pragma unroll
  for (int i = 0; i < 4; ++i) {
    int r   = i * 16 + (t >> 4);
    int col = (t & 15) << 2;
    float4 v = *reinterpret_cast<const float4*>(&xb[(size_t)r * NPIX + col]);
    sT[r][col + 0] = v.x; sT[r][col + 1] = v.y;
    sT[r][col + 2] = v.z; sT[r][col + 3] = v.w;
  }
  __syncthreads();
#pragma unroll
  for (int i = 0; i < 2; ++i) {
    int nl = t >> 2;
    int ch = (t & 3) + (i << 2);
    u16 tmp[8];
#pragma unroll
    for (int e = 0; e < 8; ++e) tmp[e] = f2bf(sT[(ch << 3) + e][nl]);
    *reinterpret_cast<uint4*>(&xt[((size_t)b * NPIX + n0 + nl) * CIN + c0 + (ch << 3)]) =
        *reinterpret_cast<uint4*>(tmp);
  }
}

// ---------------------------------------------------------------------------
// QKV GEMM (MFMA): M-tile=96 (one head), N-tile=128, BK=64, 4 waves.
// Epilogue: +bias, bf16; q PRE-SCALED by scale*log2e (attn uses exp2 domain).
// qt/kt [b][h][n][32], vt [b][h][d][n].
// ---------------------------------------------------------------------------
__global__ __launch_bounds__(256) void gemm_qkv_mfma(const u16* __restrict__ wq,
                                                     const u16* __restrict__ xt,
                                                     const float* __restrict__ bias,
                                                     u16* __restrict__ qt,
                                                     u16* __restrict__ kt,
                                                     u16* __restrict__ vt) {
  __shared__ __align__(16) u16 sA[96 * 64];
  __shared__ __align__(16) u16 sB[128 * 64];
  const int t  = threadIdx.x;
  const int w  = t >> 6, l = t & 63, g = l >> 4, ln = l & 15;
  const int n0 = blockIdx.x * 128;
  const int h  = blockIdx.y;
  const int b  = blockIdx.z;
  const int wm = w >> 1, wn = w & 1;

  const u16* wbase = wq + (size_t)h * 96 * CIN;
  const u16* xbase = xt + ((size_t)b * NPIX + n0) * CIN;

  f32x4 acc[3][4];
#pragma unroll
  for (int mi = 0; mi < 3; ++mi)
#pragma unroll
    for (int ni = 0; ni < 4; ++ni) acc[mi][ni] = {0.f, 0.f, 0.f, 0.f};

  for (int k0 = 0; k0 < CIN; k0 += 64) {
#pragma unroll
    for (int i = 0; i < 3; ++i) {
      int chunk = i * 256 + (w << 6) + l;
      gl_lds16(wbase + ((size_t)(chunk >> 3)) * CIN + k0 + ((chunk & 7) << 3),
               (char*)sA + i * 4096 + (w << 10));
    }
#pragma unroll
    for (int i = 0; i < 4; ++i) {
      int chunk = i * 256 + (w << 6) + l;
      gl_lds16(xbase + ((size_t)(chunk >> 3)) * CIN + k0 + ((chunk & 7) << 3),
               (char*)sB + i * 4096 + (w << 10));
    }
    __syncthreads();
#pragma unroll
    for (int kk = 0; kk < 64; kk += 32) {
      bf16x8 af[3], bfr[4];
#pragma unroll
      for (int mi = 0; mi < 3; ++mi)
        af[mi] = *reinterpret_cast<const bf16x8*>(&sA[(48 * wm + 16 * mi + ln) * 64 + kk + (g << 3)]);
#pragma unroll
      for (int ni = 0; ni < 4; ++ni)
        bfr[ni] = *reinterpret_cast<const bf16x8*>(&sB[((wn << 6) + (ni << 4) + ln) * 64 + kk + (g << 3)]);
#pragma unroll
      for (int mi = 0; mi < 3; ++mi)
#pragma unroll
        for (int ni = 0; ni < 4; ++ni)
          acc[mi][ni] = __builtin_amdgcn_mfma_f32_16x16x32_bf16(af[mi], bfr[ni], acc[mi][ni], 0, 0, 0);
    }
    __syncthreads();
  }

  const float QSC = 0.17677669529663687f * 1.4426950408889634f;  // scale*log2e
  const float* bh = bias + h * 96;
#pragma unroll
  for (int mi = 0; mi < 3; ++mi) {
    const int sec = 48 * wm + 16 * mi;
    const int rb  = sec + (g << 2);
    const float b0 = bh[rb + 0], b1 = bh[rb + 1], b2 = bh[rb + 2], b3 = bh[rb + 3];
#pragma unroll
    for (int ni = 0; ni < 4; ++ni) {
      const int n = n0 + (wn << 6) + (ni << 4) + ln;
      f32x4 a = acc[mi][ni];
      float v0 = a[0] + b0, v1 = a[1] + b1, v2 = a[2] + b2, v3 = a[3] + b3;
      if (sec < 32) { v0 *= QSC; v1 *= QSC; v2 *= QSC; v3 *= QSC; }
      u16 e0 = f2bf(v0), e1 = f2bf(v1), e2 = f2bf(v2), e3 = f2bf(v3);
      if (sec < 32) {
        const int d = sec + (g << 2);
        uint2 pk = make_uint2((unsigned)e0 | ((unsigned)e1 << 16),
                              (unsigned)e2 | ((unsigned)e3 << 16));
        *reinterpret_cast<uint2*>(&qt[(((size_t)(b * HEADS + h)) * NPIX + n) * DH + d]) = pk;
      } else if (sec < 64) {
        const int d = sec - 32 + (g << 2);
        uint2 pk = make_uint2((unsigned)e0 | ((unsigned)e1 << 16),
                              (unsigned)e2 | ((unsigned)e3 << 16));
        *reinterpret_cast<uint2*>(&kt[(((size_t)(b * HEADS + h)) * NPIX + n) * DH + d]) = pk;
      } else {
        const int d = sec - 64 + (g << 2);
        u16* vp = &vt[(((size_t)(b * HEADS + h)) * DH + d) * NPIX + n];
        vp[0] = e0; vp[NPIX] = e1; vp[2 * NPIX] = e2; vp[3 * NPIX] = e3;
      }
    }
  }
}

// ---------------------------------------------------------------------------
// MFMA flash attention v15 -- SWAPPED QK^T, ZERO-SHUFFLE P (no P LDS at all).
// S^T = mfma(K, Q): K is the A operand with OUR row mapping
//   fragment jj: lane(g,ln) supplies A[m=ln][k=8g..] = K[j = 32*(jj>=2) +
//   8*(ln>>2) + 4*(jj&1) + (ln&3)][d=8g..8g+7]
// so output lane(g,ln) holds P values for column i=ln at rows
//   j = 32*(jj>=2) + 8g + 4*(jj&1) + v  -- EXACTLY the A-operand k-slots
// (8g..8g+7 per 32-chunk) this lane must supply for PV. P goes exp -> bf16
// pack -> MFMA A operand, never touching LDS. Removes 4 ds_write_b64 +
// 4 ds_read_b128 + 1 lgkm round-trip per wave-step (~45% of LDS-pipe load,
// the common serializer across the r4-r13 plateau). sP freed: LDS 32KB.
// Same j-partition per accumulator -> numerically identical to r11-13.
// Block: 512 thr, 8 waves = 4 iw x 2 jh; 8 j-steps; one __syncthreads/step.
// l-sum: per-lane row i=ln partial; 2 shfl_xor at end; shfl-transpose in
// the epilogue (output rows are i=4g+v as before).
// Grid 1024: xcd=bid&7, sl=bid>>3; b=sl&3, i0=((sl>>2)&15)<<6, h=(xcd<<1)|(sl>>6).
// ---------------------------------------------------------------------------
__global__ __launch_bounds__(512, 4) void attn_mfma(const u16* __restrict__ qt,
                                                    const u16* __restrict__ kt,
                                                    const u16* __restrict__ vt,
                                                    const float* __restrict__ rel,
                                                    u16* __restrict__ aout) {
  __shared__ __align__(16) u16 sK[2][2][2048];   // [buf][jh][32r][8slot][8] 16KB
  __shared__ __align__(16) u16 sV[2][2][2048];   // [buf][jh][32d][8slot][8] 16KB

  const int t  = threadIdx.x;
  const int w  = t >> 6, l = t & 63, g = l >> 4, ln = l & 15;
  const int bid = blockIdx.x;
  const int xcd = bid & 7, sl = bid >> 3;   // sl 0..127
  const int b   = sl & 3;
  const int i0  = ((sl >> 2) & 15) << 6;
  const int h   = (xcd << 1) | (sl >> 6);
  const int iw  = w & 3;                    // i-segment (16 rows)
  const int jh  = w >> 2;                   // j-half (512 cols)

  const size_t bh = (size_t)(b * HEADS + h);

  // staging (per-thread constant): wave w stages quarter iw of j-half (w>>2).
  const int lr = l >> 3, ls = l & 7;
  const int sjh = w >> 2;
  const int kcl = ls ^ lr ^ (iw & 1);                 // K logical chunk
  const int kj  = (iw << 4) + (lr << 1) + (kcl >> 2); // j within half
  const u16* ksrc = kt + (bh * NPIX + (sjh << 9) + kj) * DH + ((kcl & 3) << 3);
  const int vcl = ls ^ lr;                            // V logical chunk
  const int vd  = (iw << 3) + lr;                     // d row
  const u16* vsrc = vt + (bh * DH + vd) * NPIX + (sjh << 9) + (vcl << 3);
  char* kdst = (char*)&sK[0][sjh][0] + (iw << 10);
  char* vdst = (char*)&sV[0][sjh][0] + (iw << 10);

#define STAGE(s_, p_) do {                                          \
    gl_lds16(ksrc + (size_t)(s_) * 2048, kdst + (p_) * 8192);       \
    gl_lds16(vsrc + (size_t)(s_) * 64,   vdst + (p_) * 8192);       \
  } while (0)

  STAGE(0, 0);

  // Q fragment (pre-scaled by scale*log2e); B operand: lane -> i=ln, k=8g..
  bf16x8 qf = *reinterpret_cast<const bf16x8*>(
      qt + (bh * NPIX + i0 + (iw << 4) + ln) * DH + (g << 3));

  // K fragment LDS offsets (per-thread constant), fragment jj:
  //   j = 32*(jj>>1) + 8*(ln>>2) + 4*(jj&1) + (ln&3)
  //   r = j>>1; c = ((j&1)<<2)|g; slot = c ^ (r&7) ^ ((r>>3)&1)
  int kOff[4];
#pragma unroll
  for (int jj = 0; jj < 4; ++jj) {
    const int j = ((jj >> 1) << 5) + ((ln >> 2) << 3) + ((jj & 1) << 2) + (ln & 3);
    const int r = j >> 1;
    const int c = ((j & 1) << 2) | g;
    const int slot = (c ^ (r & 7)) ^ ((r >> 3) & 1);
    kOff[jj] = r * 64 + slot * 8;
  }
  // V fragment offsets: (kc,dc): d=(dc<<4)+ln, chunk vc=(kc<<2)|g, slot=vc^(d&7)
  int vOff[2][2];
#pragma unroll
  for (int kc = 0; kc < 2; ++kc)
#pragma unroll
    for (int dc = 0; dc < 2; ++dc) {
      const int d = (dc << 4) + ln;
      vOff[kc][dc] = d * 64 + ((((kc << 2) | g) ^ (d & 7)) << 3);
    }

  // rel: row i0+16iw+ln, cols jh*512 + s*64 + 32kc + 8g + (0..7)
  const float* relp = rel + ((size_t)h * NPIX + i0 + (iw << 4) + ln) * NPIX +
                      (jh << 9) + (g << 3);

  f32x4 vzero = {0.f, 0.f, 0.f, 0.f};
  f32x4 accO[2] = {vzero, vzero};
  float l_part = 0.f;

  const float LOG2E = 1.4426950408889634f;

  for (int s = 0; s < 8; ++s) {
    const int p = s & 1;
    __syncthreads();                        // buf p staged; buf p^1 free
    if (s < 7) STAGE(s + 1, p ^ 1);

    // rel loads for this step: [kc][e] = f32x4 at col 32kc + 8g + 4e
    f32x4 r00 = *reinterpret_cast<const f32x4*>(relp + (s << 6));
    f32x4 r01 = *reinterpret_cast<const f32x4*>(relp + (s << 6) + 4);
    f32x4 r10 = *reinterpret_cast<const f32x4*>(relp + (s << 6) + 32);
    f32x4 r11 = *reinterpret_cast<const f32x4*>(relp + (s << 6) + 36);

    const u16* Kb = &sK[p][jh][0];
    const u16* Vb = &sV[p][jh][0];

    // ---- S^T = mfma(K, Q): fragment jj covers rows j = 32(jj>>1)+8g+4(jj&1)+v
    f32x4 sfr[4];
    __builtin_amdgcn_s_setprio(1);
#pragma unroll
    for (int jj = 0; jj < 4; ++jj) {
      bf16x8 kf = *reinterpret_cast<const bf16x8*>(Kb + kOff[jj]);
      sfr[jj] = __builtin_amdgcn_mfma_f32_16x16x32_bf16(kf, qf, vzero, 0, 0, 0);
    }
    __builtin_amdgcn_s_setprio(0);

    // ---- P = exp2(S' + rel*log2e) -> bf16 A-operands, all in registers ----
    bf16x8 pa0, pa1;
#pragma unroll
    for (int v = 0; v < 4; ++v) {
      float p0 = EXP2(fmaf(r00[v], LOG2E, sfr[0][v]));
      float p1 = EXP2(fmaf(r01[v], LOG2E, sfr[1][v]));
      float p2 = EXP2(fmaf(r10[v], LOG2E, sfr[2][v]));
      float p3 = EXP2(fmaf(r11[v], LOG2E, sfr[3][v]));
      l_part += (p0 + p1) + (p2 + p3);
      pa0[v]     = (__bf16)p0;
      pa0[4 + v] = (__bf16)p1;
      pa1[v]     = (__bf16)p2;
      pa1[4 + v] = (__bf16)p3;
    }

    // ---- PV: acc[dc] += pa(kc) x V(kc,dc) ----
    __builtin_amdgcn_s_setprio(1);
    {
      bf16x8 vf00 = *reinterpret_cast<const bf16x8*>(Vb + vOff[0][0]);
      bf16x8 vf01 = *reinterpret_cast<const bf16x8*>(Vb + vOff[0][1]);
      accO[0] = __builtin_amdgcn_mfma_f32_16x16x32_bf16(pa0, vf00, accO[0], 0, 0, 0);
      accO[1] = __builtin_amdgcn_mfma_f32_16x16x32_bf16(pa0, vf01, accO[1], 0, 0, 0);
      bf16x8 vf10 = *reinterpret_cast<const bf16x8*>(Vb + vOff[1][0]);
      bf16x8 vf11 = *reinterpret_cast<const bf16x8*>(Vb + vOff[1][1]);
      accO[0] = __builtin_amdgcn_mfma_f32_16x16x32_bf16(pa1, vf10, accO[0], 0, 0, 0);
      accO[1] = __builtin_amdgcn_mfma_f32_16x16x32_bf16(pa1, vf11, accO[1], 0, 0, 0);
    }
    __builtin_amdgcn_s_setprio(0);
  }
#undef STAGE

  // ---- reduce l over the 4 g-groups: every lane -> rowsum(i=ln) of its jh
  l_part += __shfl_xor(l_part, 16);
  l_part += __shfl_xor(l_part, 32);

  // ---- merge the two j-halves, then finalize (jh==0 waves write out) ----
  __syncthreads();
  float* mrg = (float*)&sK[0][0][0];        // 12.3 KB scratch over sK space
  if (jh == 1) {
    float* mp = mrg + ((size_t)((iw << 6) + l)) * 12;
    *reinterpret_cast<f32x4*>(mp + 0) = accO[0];
    *reinterpret_cast<f32x4*>(mp + 4) = accO[1];
    mp[8] = l_part;
  }
  __syncthreads();
  if (jh == 0) {
    const float* mp = mrg + ((size_t)((iw << 6) + l)) * 12;
    f32x4 o0 = accO[0] + *reinterpret_cast<const f32x4*>(mp + 0);
    f32x4 o1 = accO[1] + *reinterpret_cast<const f32x4*>(mp + 4);
    float lsum = l_part + mp[8];            // total rowsum for i = ln
#pragma unroll
    for (int v = 0; v < 4; ++v) {
      const float lrow = __shfl(lsum, (g << 2) + v);   // rowsum(i = 4g+v)
      const float inv = 1.f / lrow;
      const size_t row = (size_t)b * NPIX + i0 + (iw << 4) + (g << 2) + v;
      aout[row * DATTN + (h << 5) + ln]      = f2bf(o0[v] * inv);
      aout[row * DATTN + (h << 5) + 16 + ln] = f2bf(o1[v] * inv);
    }
  }
}

// ---------------------------------------------------------------------------
// Proj GEMM (MFMA): out[b][o][n] = sum_k Wp[o,k] * A[b][n][k] + bias[o], f32 out.
// ---------------------------------------------------------------------------
__global__ __launch_bounds__(256) void gemm_proj_mfma(const u16* __restrict__ wp,
                                                      const u16* __restrict__ at,
                                                      const float* __restrict__ bias,
                                                      float* __restrict__ out) {
  __shared__ __align__(16) u16 sA[64 * 64];
  __shared__ __align__(16) u16 sB[128 * 64];
  const int t  = threadIdx.x;
  const int w  = t >> 6, l = t & 63, g = l >> 4, ln = l & 15;
  const int n0 = blockIdx.x * 128;
  const int o0 = blockIdx.y * 64;
  const int b  = blockIdx.z;
  const int wm = w >> 1, wn = w & 1;

  const u16* wbase = wp + (size_t)o0 * DATTN;
  const u16* abase = at + ((size_t)b * NPIX + n0) * DATTN;

  f32x4 acc[2][4];
#pragma unroll
  for (int mi = 0; mi < 2; ++mi)
#pragma unroll
    for (int ni = 0; ni < 4; ++ni) acc[mi][ni] = {0.f, 0.f, 0.f, 0.f};

  for (int k0 = 0; k0 < DATTN; k0 += 64) {
#pragma unroll
    for (int i = 0; i < 2; ++i) {
      int chunk = i * 256 + (w << 6) + l;
      gl_lds16(wbase + ((size_t)(chunk >> 3)) * DATTN + k0 + ((chunk & 7) << 3),
               (char*)sA + i * 4096 + (w << 10));
    }
#pragma unroll
    for (int i = 0; i < 4; ++i) {
      int chunk = i * 256 + (w << 6) + l;
      gl_lds16(abase + ((size_t)(chunk >> 3)) * DATTN + k0 + ((chunk & 7) << 3),
               (char*)sB + i * 4096 + (w << 10));
    }
    __syncthreads();
#pragma unroll
    for (int kk = 0; kk < 64; kk += 32) {
      bf16x8 af[2], bfr[4];
#pragma unroll
      for (int mi = 0; mi < 2; ++mi)
        af[mi] = *reinterpret_cast<const bf16x8*>(&sA[((wm << 5) + (mi << 4) + ln) * 64 + kk + (g << 3)]);
#pragma unroll
      for (int ni = 0; ni < 4; ++ni)
        bfr[ni] = *reinterpret_cast<const bf16x8*>(&sB[((wn << 6) + (ni << 4) + ln) * 64 + kk + (g << 3)]);
#pragma unroll
      for (int mi = 0; mi < 2; ++mi)
#pragma unroll
        for (int ni = 0; ni < 4; ++ni)
          acc[mi][ni] = __builtin_amdgcn_mfma_f32_16x16x32_bf16(af[mi], bfr[ni], acc[mi][ni], 0, 0, 0);
    }
    __syncthreads();
  }

#pragma unroll
  for (int mi = 0; mi < 2; ++mi) {
    const int o = o0 + (wm << 5) + (mi << 4) + (g << 2);
    const float b0 = bias[o], b1 = bias[o + 1], b2 = bias[o + 2], b3 = bias[o + 3];
#pragma unroll
    for (int ni = 0; ni < 4; ++ni) {
      const int n = n0 + (wn << 6) + (ni << 4) + ln;
      float* op = &out[((size_t)b * DATTN + o) * NPIX + n];
      op[0]        = acc[mi][ni][0] + b0;
      op[NPIX]     = acc[mi][ni][1] + b1;
      op[2 * NPIX] = acc[mi][ni][2] + b2;
      op[3 * NPIX] = acc[mi][ni][3] + b3;
    }
  }
}

extern "C" void kernel_launch(void* const* d_in, const int* in_sizes, int n_in,
                              void* d_out, int out_size, void* d_ws, size_t ws_size,
                              hipStream_t stream) {
  (void)in_sizes; (void)n_in; (void)out_size; (void)ws_size;
  const float* x      = (const float*)d_in[0];
  const float* w_qkv  = (const float*)d_in[1];
  const float* b_qkv  = (const float*)d_in[2];
  const float* w_proj = (const float*)d_in[3];
  const float* b_proj = (const float*)d_in[4];
  const float* rel    = (const float*)d_in[5];
  float* out = (float*)d_out;

  u16* xt    = (u16*)d_ws;                                   // 4 MB
  u16* wq_bf = xt + (size_t)BATCH * NPIX * CIN;              // 1.5 MB
  u16* wp_bf = wq_bf + (size_t)O_QKV * CIN;                  // 0.5 MB
  u16* qt    = wp_bf + (size_t)DATTN * DATTN;                // 4 MB
  u16* kt    = qt + (size_t)BATCH * HEADS * NPIX * DH;       // 4 MB
  u16* vt    = kt + (size_t)BATCH * HEADS * NPIX * DH;       // 4 MB
  u16* aout  = vt + (size_t)BATCH * HEADS * NPIX * DH;       // 4 MB

  prep_w<<<1024, 256, 0, stream>>>(w_qkv, w_proj, wq_bf, wp_bf);
  prep_x<<<dim3(NPIX / 64, CIN / 64, BATCH), 256, 0, stream>>>(x, xt);
  gemm_qkv_mfma<<<dim3(NPIX / 128, HEADS, BATCH), 256, 0, stream>>>(wq_bf, xt, b_qkv, qt, kt, vt);
  attn_mfma<<<1024, 512, 0, stream>>>(qt, kt, vt, rel, aout);
  gemm_proj_mfma<<<dim3(NPIX / 128, DATTN / 64, BATCH), 256, 0, stream>>>(wp_bf, aout, b_proj, out);
}